// Round 10
// baseline (309.432 us; speedup 1.0000x reference)
//
#include <hip/hip_runtime.h>
#include <hip/hip_fp16.h>
#include <cstdint>
#include <cstddef>

#define B_ 512
#define T_ 256
#define N_ 128
#define H_ 64
#define G_ 256  // 4H

typedef __attribute__((ext_vector_type(8))) short short8;
typedef __attribute__((ext_vector_type(4))) float f32x4;
typedef _Float16 half2_t __attribute__((ext_vector_type(2)));

static __device__ __forceinline__ unsigned short f2bf(float f) {
    union { float f; unsigned int i; } v;
    v.f = f;
    unsigned int x = v.i;
    return (unsigned short)((x + 0x7fffu + ((x >> 16) & 1u)) >> 16);  // RNE
}
static __device__ __forceinline__ half2_t u2h2(unsigned int u) {
    union { unsigned int u; half2_t h; } v; v.u = u; return v.h;
}

// ---------------------------------------------------------------------------
// K0: pack W_hh (f32 [4H][H]) -> wpack uint4 [4][8][64]: wpack[g][q][j] =
// half2x4 of W_hh[g*64+j][8q..8q+7].  Exactly the per-lane order k_rnn8 loads.
// ---------------------------------------------------------------------------
__global__ __launch_bounds__(256) void k_wpack(const float* __restrict__ W_hh,
                                               uint4* __restrict__ wpack) {
    int idx = blockIdx.x * 256 + threadIdx.x;   // 2048 entries
    if (idx >= 2048) return;
    int g = idx >> 9, q = (idx >> 6) & 7, j = idx & 63;
    const float* src = W_hh + ((size_t)(g * H_ + j)) * H_ + q * 8;
    float4 a = *(const float4*)(src);
    float4 b = *(const float4*)(src + 4);
    union { uint4 u; half2_t h[4]; } pk;
    pk.h[0] = (half2_t){(_Float16)a.x, (_Float16)a.y};
    pk.h[1] = (half2_t){(_Float16)a.z, (_Float16)a.w};
    pk.h[2] = (half2_t){(_Float16)b.x, (_Float16)b.y};
    pk.h[3] = (half2_t){(_Float16)b.z, (_Float16)b.w};
    wpack[idx] = pk.u;
}

// ---------------------------------------------------------------------------
// K1+K2 fused (unchanged: ~50us, BW floor ~37us — later target).
// ---------------------------------------------------------------------------
__global__ __launch_bounds__(256) void k_awgemm(const float* __restrict__ x,
                                                const float* __restrict__ attn_w,
                                                const float* __restrict__ W_ih,
                                                const float* __restrict__ b_ih,
                                                const float* __restrict__ b_hh,
                                                float* __restrict__ iw,
                                                _Float16* __restrict__ gatesx) {
    __shared__ __align__(16) unsigned short Wl[G_][136];  // bf16 W_ih, padded
    __shared__ __align__(16) unsigned short Al[32][136];  // bf16 wx tile (overlaid: red)
    __shared__ float bias[G_];
    __shared__ float aw_s[T_];
    __shared__ float a_s[N_];
    __shared__ float wred[4];
    const int tid = threadIdx.x;
    const int b = blockIdx.x;

    for (int q = tid; q < G_ * 32; q += 256) {
        int r = q >> 5, c4 = (q & 31) << 2;
        float4 v = *(const float4*)(W_ih + r * N_ + c4);
        Wl[r][c4 + 0] = f2bf(v.x); Wl[r][c4 + 1] = f2bf(v.y);
        Wl[r][c4 + 2] = f2bf(v.z); Wl[r][c4 + 3] = f2bf(v.w);
    }
    bias[tid] = b_ih[tid] + b_hh[tid];
    aw_s[tid] = attn_w[2 * H_ + tid];
    __syncthreads();

    // ---- Phase A: attention softmax (shift-invariance kills h/c/bias) ----
    float (*red)[128] = (float(*)[128])&Al[0][0];
    const int n0 = (tid & 31) << 2;
    const int tg = tid >> 5;
    const float* xb = x + (size_t)b * (T_ * N_);
    {
        float p0 = 0.f, p1 = 0.f, p2 = 0.f, p3 = 0.f;
        for (int t = tg; t < T_; t += 8) {
            float4 v = *(const float4*)(xb + t * N_ + n0);
            float w = aw_s[t];
            p0 += v.x * w; p1 += v.y * w; p2 += v.z * w; p3 += v.w * w;
        }
        red[tg][n0 + 0] = p0; red[tg][n0 + 1] = p1;
        red[tg][n0 + 2] = p2; red[tg][n0 + 3] = p3;
    }
    __syncthreads();
    {
        float s = 0.f;
        if (tid < 128) {
            #pragma unroll
            for (int g = 0; g < 8; ++g) s += red[g][tid];
        }
        float m = (tid < 128) ? s : -1e30f;
        #pragma unroll
        for (int d = 1; d < 64; d <<= 1) m = fmaxf(m, __shfl_xor(m, d));
        if ((tid & 63) == 0) wred[tid >> 6] = m;
        __syncthreads();
        m = fmaxf(wred[0], wred[1]);
        __syncthreads();
        float e = (tid < 128) ? __expf(s - m) : 0.f;
        float z = e;
        #pragma unroll
        for (int d = 1; d < 64; d <<= 1) z += __shfl_xor(z, d);
        if ((tid & 63) == 0) wred[tid >> 6] = z;
        __syncthreads();
        z = wred[0] + wred[1];
        if (tid < 128) a_s[tid] = e / z;
    }
    __syncthreads();

    // ---- Phase B: weighting + MFMA GEMM ----
    const int lane = tid & 63;
    const int lr = lane & 15;
    const int lk = (lane >> 4) << 3;
    const int gc0 = (tid >> 6) << 6;
    const int orow = (lane >> 4) << 2;

    for (int st = 0; st < 8; ++st) {
        const int r0 = b * T_ + st * 32;
        __syncthreads();
        for (int q = tid; q < 32 * 32; q += 256) {
            int r = q >> 5, c4 = (q & 31) << 2;
            size_t off = (size_t)(r0 + r) * N_ + c4;
            float4 v = *(const float4*)(x + off);
            float4 w;
            w.x = a_s[c4 + 0] * v.x; w.y = a_s[c4 + 1] * v.y;
            w.z = a_s[c4 + 2] * v.z; w.w = a_s[c4 + 3] * v.w;
            *(float4*)(iw + off) = w;            // output 0 (f32, exact)
            Al[r][c4 + 0] = f2bf(w.x); Al[r][c4 + 1] = f2bf(w.y);
            Al[r][c4 + 2] = f2bf(w.z); Al[r][c4 + 3] = f2bf(w.w);
        }
        __syncthreads();

        f32x4 acc[2][4];
        #pragma unroll
        for (int mt = 0; mt < 2; ++mt)
            #pragma unroll
            for (int nt = 0; nt < 4; ++nt)
                acc[mt][nt] = (f32x4){0.f, 0.f, 0.f, 0.f};

        #pragma unroll
        for (int kk = 0; kk < N_; kk += 32) {
            short8 af0 = *(const short8*)(&Al[lr][kk + lk]);
            short8 af1 = *(const short8*)(&Al[16 + lr][kk + lk]);
            #pragma unroll
            for (int nt = 0; nt < 4; ++nt) {
                short8 bfv = *(const short8*)(&Wl[gc0 + nt * 16 + lr][kk + lk]);
                acc[0][nt] = __builtin_amdgcn_mfma_f32_16x16x32_bf16(af0, bfv, acc[0][nt], 0, 0, 0);
                acc[1][nt] = __builtin_amdgcn_mfma_f32_16x16x32_bf16(af1, bfv, acc[1][nt], 0, 0, 0);
            }
        }
        // D: col = gc0+nt*16+lr (gate index), row = mt*16+(lane>>4)*4+reg
        #pragma unroll
        for (int mt = 0; mt < 2; ++mt) {
            #pragma unroll
            for (int nt = 0; nt < 4; ++nt) {
                int col = gc0 + nt * 16 + lr;
                float bs = bias[col];
                int cell = col & 63, qg = col >> 6;
                #pragma unroll
                for (int rg = 0; rg < 4; ++rg) {
                    int rr = r0 + mt * 16 + orow + rg;
                    gatesx[((size_t)rr * H_ + cell) * 4 + qg] =
                        (_Float16)(acc[mt][nt][rg] + bs);
                }
            }
        }
    }
}

// ---------------------------------------------------------------------------
// K3: LSTM recurrence, TWO batches per wave, interleaved. 256 blocks x 64 thr.
// Round-9 lesson: single wave/SIMD has zero TLP; ~850cy/step of dependency
// latency (fdot2 chains, readlane hazards, trans tail) is fully exposed —
// unrolling can't fix it. W_hh is SHARED across batches, so one wave runs two
// independent recurrences from the same 128 weight VGPRs: 8 interleaved fdot2
// chains + 2 overlapping trans tails. Chain A's stalls are filled by chain B.
// ---------------------------------------------------------------------------
__global__ __attribute__((amdgpu_flat_work_group_size(64, 64)))
__attribute__((amdgpu_waves_per_eu(1, 1)))
void k_rnn8(const _Float16* __restrict__ gatesx,
            const uint4* __restrict__ wpack,
            float* __restrict__ enc) {
    const int j = threadIdx.x;   // cell index
    const int b0 = blockIdx.x * 2;

    // 32 x dwordx4 = 128 VGPRs of packed half2 weights (shared by both batches)
    uint4 wv[4][8];
    #pragma unroll
    for (int g = 0; g < 4; ++g) {
        #pragma unroll
        for (int q = 0; q < 8; ++q) {
            unsigned voff = (unsigned)((((g << 3) + q) * 64 + j) << 4);
            asm volatile("global_load_dwordx4 %0, %1, %2"
                         : "=v"(wv[g][q]) : "v"(voff), "s"(wpack) : "memory");
        }
    }
    asm volatile("s_waitcnt vmcnt(0)" ::: "memory");

    float c0 = 0.f, c1 = 0.f;
    unsigned hpk0 = 0u, hpk1 = 0u;    // lane-pair packed f16 h; h_{-1}=0
    const bool even = ((j & 1) == 0);

    const _Float16* gx0 = gatesx + ((size_t)b0 * T_ * H_ + j) * 4;
    const _Float16* gx1 = gx0 + (size_t)T_ * G_;
    float* ep0 = enc + (size_t)b0 * T_ * H_ + j;
    float* ep1 = ep0 + (size_t)T_ * H_;

    uint2 gA0 = *(const uint2*)(gx0);          // batch0, t=0
    uint2 gA1 = *(const uint2*)(gx1);          // batch1, t=0
    uint2 gB0 = *(const uint2*)(gx0 + G_);     // batch0, t=1
    uint2 gB1 = *(const uint2*)(gx1 + G_);     // batch1, t=1

    // one readlane+4-fdot2 group per batch, alternating -> 8 indep chains
#define DOT2(m, w0_, w1_, w2_, w3_)                                          \
        do {                                                                 \
            unsigned h0_ = (unsigned)__builtin_amdgcn_readlane((int)hpk0, 2 * (m)); \
            half2_t hh0_ = u2h2(h0_);                                        \
            a00 = __builtin_amdgcn_fdot2(u2h2(w0_), hh0_, a00, false);       \
            a01 = __builtin_amdgcn_fdot2(u2h2(w1_), hh0_, a01, false);       \
            a02 = __builtin_amdgcn_fdot2(u2h2(w2_), hh0_, a02, false);       \
            a03 = __builtin_amdgcn_fdot2(u2h2(w3_), hh0_, a03, false);       \
            unsigned h1_ = (unsigned)__builtin_amdgcn_readlane((int)hpk1, 2 * (m)); \
            half2_t hh1_ = u2h2(h1_);                                        \
            a10 = __builtin_amdgcn_fdot2(u2h2(w0_), hh1_, a10, false);       \
            a11 = __builtin_amdgcn_fdot2(u2h2(w1_), hh1_, a11, false);       \
            a12 = __builtin_amdgcn_fdot2(u2h2(w2_), hh1_, a12, false);       \
            a13 = __builtin_amdgcn_fdot2(u2h2(w3_), hh1_, a13, false);       \
        } while (0)

#define CELL(A0, A1, A2, A3, CREG, HPK, EP)                                  \
    {                                                                        \
        float si = 1.f / (1.f + __expf(-(A0)));                              \
        float sf = 1.f / (1.f + __expf(-(A1)));                              \
        float tg = 1.f - 2.f / (__expf(2.f * (A2)) + 1.f);                   \
        float so = 1.f / (1.f + __expf(-(A3)));                              \
        CREG = sf * CREG + si * tg;                                          \
        float tc = 1.f - 2.f / (__expf(2.f * CREG) + 1.f);                   \
        float h = so * tc;                                                   \
        union { _Float16 hf; unsigned short u; } cv_; cv_.hf = (_Float16)h;  \
        unsigned hf_ = cv_.u;                                                \
        unsigned nb_ = (unsigned)__builtin_amdgcn_mov_dpp((int)hf_, 0xB1, 0xF, 0xF, true); \
        HPK = even ? (hf_ | (nb_ << 16)) : (nb_ | (hf_ << 16));              \
        *(EP) = h;                                                           \
        (EP) += H_;                                                          \
    }

    // one time-step for BOTH batches, fully interleaved
#define PAIR_STEP(GR0, GR1, TNEXT)                                           \
    {                                                                        \
        half2_t gi0 = u2h2(GR0.x), go0 = u2h2(GR0.y);                        \
        half2_t gi1 = u2h2(GR1.x), go1 = u2h2(GR1.y);                        \
        float a00 = (float)gi0.x, a01 = (float)gi0.y;                        \
        float a02 = (float)go0.x, a03 = (float)go0.y;                        \
        float a10 = (float)gi1.x, a11 = (float)gi1.y;                        \
        float a12 = (float)go1.x, a13 = (float)go1.y;                        \
        int tn_ = (TNEXT) < T_ ? (TNEXT) : (T_ - 1);                         \
        GR0 = *(const uint2*)(gx0 + (size_t)tn_ * G_);                       \
        GR1 = *(const uint2*)(gx1 + (size_t)tn_ * G_);                       \
        _Pragma("unroll")                                                    \
        for (int q = 0; q < 8; ++q) {                                        \
            DOT2(4 * q + 0, wv[0][q].x, wv[1][q].x, wv[2][q].x, wv[3][q].x); \
            DOT2(4 * q + 1, wv[0][q].y, wv[1][q].y, wv[2][q].y, wv[3][q].y); \
            DOT2(4 * q + 2, wv[0][q].z, wv[1][q].z, wv[2][q].z, wv[3][q].z); \
            DOT2(4 * q + 3, wv[0][q].w, wv[1][q].w, wv[2][q].w, wv[3][q].w); \
        }                                                                    \
        CELL(a00, a01, a02, a03, c0, hpk0, ep0);                             \
        CELL(a10, a11, a12, a13, c1, hpk1, ep1);                             \
    }

    for (int t = 0; t < T_; t += 2) {
        PAIR_STEP(gA0, gA1, t + 2);
        PAIR_STEP(gB0, gB1, t + 3);
    }
#undef PAIR_STEP
#undef CELL
#undef DOT2
}

extern "C" void kernel_launch(void* const* d_in, const int* in_sizes, int n_in,
                              void* d_out, int out_size, void* d_ws, size_t ws_size,
                              hipStream_t stream) {
    if (n_in < 7 || in_sizes[0] != B_ * T_ * N_) return;

    const float* x    = (const float*)d_in[0];
    const float* aw   = (const float*)d_in[1];
    // d_in[2] (attn_b) provably cancels in the softmax — unused.
    const float* W_ih = (const float*)d_in[3];
    const float* W_hh = (const float*)d_in[4];
    const float* b_ih = (const float*)d_in[5];
    const float* b_hh = (const float*)d_in[6];

    float* iwp = (float*)d_out;                          // (B,T,N) f32
    float* enc = (float*)d_out + (size_t)B_ * T_ * N_;   // (B,T,H) f32

    size_t gx_bytes = (size_t)B_ * T_ * G_ * sizeof(_Float16);   // 33.5 MB
    _Float16* gatesx = (_Float16*)d_ws;
    uint4* wpack = (uint4*)((char*)d_ws + gx_bytes);             // 32 KB
    size_t need = gx_bytes + 2048 * sizeof(uint4);
    if (ws_size < need) return;  // fail loudly rather than corrupt

    hipLaunchKernelGGL(k_wpack, dim3(8), dim3(256), 0, stream, W_hh, wpack);
    hipLaunchKernelGGL(k_awgemm, dim3(B_), dim3(256), 0, stream,
                       x, aw, W_ih, b_ih, b_hh, iwp, gatesx);
    hipLaunchKernelGGL(k_rnn8, dim3(B_ / 2), dim3(64), 0, stream, gatesx, wpack, enc);
}

// Round 11
// 195.686 us; speedup vs baseline: 1.5813x; 1.5813x over previous
//
#include <hip/hip_runtime.h>
#include <hip/hip_fp16.h>
#include <cstdint>
#include <cstddef>

#define B_ 512
#define T_ 256
#define N_ 128
#define H_ 64
#define G_ 256  // 4H

typedef __attribute__((ext_vector_type(8))) short short8;
typedef __attribute__((ext_vector_type(4))) float f32x4;
typedef _Float16 half2_t __attribute__((ext_vector_type(2)));

static __device__ __forceinline__ unsigned short f2bf(float f) {
    union { float f; unsigned int i; } v;
    v.f = f;
    unsigned int x = v.i;
    return (unsigned short)((x + 0x7fffu + ((x >> 16) & 1u)) >> 16);  // RNE
}
static __device__ __forceinline__ half2_t u2h2(unsigned int u) {
    union { unsigned int u; half2_t h; } v; v.u = u; return v.h;
}

// ---------------------------------------------------------------------------
// K0: pack W_hh (f32 [4H][H]) -> wpack uint4 [4][8][64]: wpack[g][q][j] =
// half2x4 of W_hh[g*64+j][8q..8q+7].  Exactly the per-lane order k_rnn9 loads.
// ---------------------------------------------------------------------------
__global__ __launch_bounds__(256) void k_wpack(const float* __restrict__ W_hh,
                                               uint4* __restrict__ wpack) {
    int idx = blockIdx.x * 256 + threadIdx.x;   // 2048 entries
    if (idx >= 2048) return;
    int g = idx >> 9, q = (idx >> 6) & 7, j = idx & 63;
    const float* src = W_hh + ((size_t)(g * H_ + j)) * H_ + q * 8;
    float4 a = *(const float4*)(src);
    float4 b = *(const float4*)(src + 4);
    union { uint4 u; half2_t h[4]; } pk;
    pk.h[0] = (half2_t){(_Float16)a.x, (_Float16)a.y};
    pk.h[1] = (half2_t){(_Float16)a.z, (_Float16)a.w};
    pk.h[2] = (half2_t){(_Float16)b.x, (_Float16)b.y};
    pk.h[3] = (half2_t){(_Float16)b.z, (_Float16)b.w};
    wpack[idx] = pk.u;
}

// ---------------------------------------------------------------------------
// K1+K2 fused (unchanged: ~50us, BW floor ~37us — later target).
// ---------------------------------------------------------------------------
__global__ __launch_bounds__(256) void k_awgemm(const float* __restrict__ x,
                                                const float* __restrict__ attn_w,
                                                const float* __restrict__ W_ih,
                                                const float* __restrict__ b_ih,
                                                const float* __restrict__ b_hh,
                                                float* __restrict__ iw,
                                                _Float16* __restrict__ gatesx) {
    __shared__ __align__(16) unsigned short Wl[G_][136];  // bf16 W_ih, padded
    __shared__ __align__(16) unsigned short Al[32][136];  // bf16 wx tile (overlaid: red)
    __shared__ float bias[G_];
    __shared__ float aw_s[T_];
    __shared__ float a_s[N_];
    __shared__ float wred[4];
    const int tid = threadIdx.x;
    const int b = blockIdx.x;

    for (int q = tid; q < G_ * 32; q += 256) {
        int r = q >> 5, c4 = (q & 31) << 2;
        float4 v = *(const float4*)(W_ih + r * N_ + c4);
        Wl[r][c4 + 0] = f2bf(v.x); Wl[r][c4 + 1] = f2bf(v.y);
        Wl[r][c4 + 2] = f2bf(v.z); Wl[r][c4 + 3] = f2bf(v.w);
    }
    bias[tid] = b_ih[tid] + b_hh[tid];
    aw_s[tid] = attn_w[2 * H_ + tid];
    __syncthreads();

    // ---- Phase A: attention softmax (shift-invariance kills h/c/bias) ----
    float (*red)[128] = (float(*)[128])&Al[0][0];
    const int n0 = (tid & 31) << 2;
    const int tg = tid >> 5;
    const float* xb = x + (size_t)b * (T_ * N_);
    {
        float p0 = 0.f, p1 = 0.f, p2 = 0.f, p3 = 0.f;
        for (int t = tg; t < T_; t += 8) {
            float4 v = *(const float4*)(xb + t * N_ + n0);
            float w = aw_s[t];
            p0 += v.x * w; p1 += v.y * w; p2 += v.z * w; p3 += v.w * w;
        }
        red[tg][n0 + 0] = p0; red[tg][n0 + 1] = p1;
        red[tg][n0 + 2] = p2; red[tg][n0 + 3] = p3;
    }
    __syncthreads();
    {
        float s = 0.f;
        if (tid < 128) {
            #pragma unroll
            for (int g = 0; g < 8; ++g) s += red[g][tid];
        }
        float m = (tid < 128) ? s : -1e30f;
        #pragma unroll
        for (int d = 1; d < 64; d <<= 1) m = fmaxf(m, __shfl_xor(m, d));
        if ((tid & 63) == 0) wred[tid >> 6] = m;
        __syncthreads();
        m = fmaxf(wred[0], wred[1]);
        __syncthreads();
        float e = (tid < 128) ? __expf(s - m) : 0.f;
        float z = e;
        #pragma unroll
        for (int d = 1; d < 64; d <<= 1) z += __shfl_xor(z, d);
        if ((tid & 63) == 0) wred[tid >> 6] = z;
        __syncthreads();
        z = wred[0] + wred[1];
        if (tid < 128) a_s[tid] = e / z;
    }
    __syncthreads();

    // ---- Phase B: weighting + MFMA GEMM ----
    const int lane = tid & 63;
    const int lr = lane & 15;
    const int lk = (lane >> 4) << 3;
    const int gc0 = (tid >> 6) << 6;
    const int orow = (lane >> 4) << 2;

    for (int st = 0; st < 8; ++st) {
        const int r0 = b * T_ + st * 32;
        __syncthreads();
        for (int q = tid; q < 32 * 32; q += 256) {
            int r = q >> 5, c4 = (q & 31) << 2;
            size_t off = (size_t)(r0 + r) * N_ + c4;
            float4 v = *(const float4*)(x + off);
            float4 w;
            w.x = a_s[c4 + 0] * v.x; w.y = a_s[c4 + 1] * v.y;
            w.z = a_s[c4 + 2] * v.z; w.w = a_s[c4 + 3] * v.w;
            *(float4*)(iw + off) = w;            // output 0 (f32, exact)
            Al[r][c4 + 0] = f2bf(w.x); Al[r][c4 + 1] = f2bf(w.y);
            Al[r][c4 + 2] = f2bf(w.z); Al[r][c4 + 3] = f2bf(w.w);
        }
        __syncthreads();

        f32x4 acc[2][4];
        #pragma unroll
        for (int mt = 0; mt < 2; ++mt)
            #pragma unroll
            for (int nt = 0; nt < 4; ++nt)
                acc[mt][nt] = (f32x4){0.f, 0.f, 0.f, 0.f};

        #pragma unroll
        for (int kk = 0; kk < N_; kk += 32) {
            short8 af0 = *(const short8*)(&Al[lr][kk + lk]);
            short8 af1 = *(const short8*)(&Al[16 + lr][kk + lk]);
            #pragma unroll
            for (int nt = 0; nt < 4; ++nt) {
                short8 bfv = *(const short8*)(&Wl[gc0 + nt * 16 + lr][kk + lk]);
                acc[0][nt] = __builtin_amdgcn_mfma_f32_16x16x32_bf16(af0, bfv, acc[0][nt], 0, 0, 0);
                acc[1][nt] = __builtin_amdgcn_mfma_f32_16x16x32_bf16(af1, bfv, acc[1][nt], 0, 0, 0);
            }
        }
        // D: col = gc0+nt*16+lr (gate index), row = mt*16+(lane>>4)*4+reg
        #pragma unroll
        for (int mt = 0; mt < 2; ++mt) {
            #pragma unroll
            for (int nt = 0; nt < 4; ++nt) {
                int col = gc0 + nt * 16 + lr;
                float bs = bias[col];
                int cell = col & 63, qg = col >> 6;
                #pragma unroll
                for (int rg = 0; rg < 4; ++rg) {
                    int rr = r0 + mt * 16 + orow + rg;
                    gatesx[((size_t)rr * H_ + cell) * 4 + qg] =
                        (_Float16)(acc[mt][nt][rg] + bs);
                }
            }
        }
    }
}

// ---------------------------------------------------------------------------
// K3: LSTM recurrence, single-wave blocks (64 thr), 512 blocks, zero LDS.
// Round-10 lesson: 2-batch interleave was DE-interleaved by the register
// allocator (VGPR stayed 132) -> regression. Root-cause hunt for the ~850cy
// stall instead: k_rnn7's dot used ONE accumulator per gate = a 32-deep
// dependent fdot2 chain with only 4-way ILP; at ~16cy dep latency that is
// ~500cy latency-bound, + readlane->fdot2 SGPR hazards + trans tail = ~1250.
// Fix: FOUR partial accumulators per gate (16 independent 8-deep chains;
// dependent uses 32cy apart -> latency covered), tree-combine at the end.
// ---------------------------------------------------------------------------
__global__ __attribute__((amdgpu_flat_work_group_size(64, 64)))
__attribute__((amdgpu_waves_per_eu(1, 1)))
void k_rnn9(const _Float16* __restrict__ gatesx,
            const uint4* __restrict__ wpack,
            float* __restrict__ enc) {
    const int j = threadIdx.x;   // cell index
    const int b = blockIdx.x;

    // 32 x dwordx4 = 128 VGPRs of packed half2 weights (4 gate rows x 8 quads)
    uint4 wv[4][8];
    #pragma unroll
    for (int g = 0; g < 4; ++g) {
        #pragma unroll
        for (int q = 0; q < 8; ++q) {
            unsigned voff = (unsigned)((((g << 3) + q) * 64 + j) << 4);
            asm volatile("global_load_dwordx4 %0, %1, %2"
                         : "=v"(wv[g][q]) : "v"(voff), "s"(wpack) : "memory");
        }
    }
    asm volatile("s_waitcnt vmcnt(0)" ::: "memory");

    float c = 0.f;
    unsigned hpk = 0u;                 // lane-pair packed f16 (h[2m], h[2m+1]); h_{-1}=0
    const bool even = ((j & 1) == 0);

    const _Float16* gx = gatesx + ((size_t)b * T_ * H_ + j) * 4;
    float* ep = enc + (size_t)b * T_ * H_ + j;

    uint2 gA = *(const uint2*)(gx);            // t = 0
    uint2 gB = *(const uint2*)(gx + G_);       // t = 1

    // one readlane-group: partial accumulators pa[gate][e], e = m&3.
#define DOTQ(q, e, COMP)                                                    \
        do {                                                                \
            unsigned hs_ = (unsigned)__builtin_amdgcn_readlane((int)hpk, 2 * (4 * (q) + (e))); \
            half2_t hh_ = u2h2(hs_);                                        \
            pa[0][e] = __builtin_amdgcn_fdot2(u2h2(wv[0][q].COMP), hh_, pa[0][e], false); \
            pa[1][e] = __builtin_amdgcn_fdot2(u2h2(wv[1][q].COMP), hh_, pa[1][e], false); \
            pa[2][e] = __builtin_amdgcn_fdot2(u2h2(wv[2][q].COMP), hh_, pa[2][e], false); \
            pa[3][e] = __builtin_amdgcn_fdot2(u2h2(wv[3][q].COMP), hh_, pa[3][e], false); \
        } while (0)

#define STEP(GREG, TNEXT)                                                   \
    {                                                                       \
        half2_t gif = u2h2(GREG.x), ggo = u2h2(GREG.y);                     \
        float pa[4][4];                                                     \
        pa[0][0] = (float)gif.x; pa[1][0] = (float)gif.y;                   \
        pa[2][0] = (float)ggo.x; pa[3][0] = (float)ggo.y;                   \
        _Pragma("unroll")                                                   \
        for (int g_ = 0; g_ < 4; ++g_) {                                    \
            pa[g_][1] = 0.f; pa[g_][2] = 0.f; pa[g_][3] = 0.f;              \
        }                                                                   \
        int tn_ = (TNEXT) < T_ ? (TNEXT) : (T_ - 1);                        \
        GREG = *(const uint2*)(gx + (size_t)tn_ * G_);                      \
        _Pragma("unroll")                                                   \
        for (int q = 0; q < 8; ++q) {                                       \
            DOTQ(q, 0, x); DOTQ(q, 1, y); DOTQ(q, 2, z); DOTQ(q, 3, w);     \
        }                                                                   \
        float a0 = (pa[0][0] + pa[0][1]) + (pa[0][2] + pa[0][3]);           \
        float a1 = (pa[1][0] + pa[1][1]) + (pa[1][2] + pa[1][3]);           \
        float a2 = (pa[2][0] + pa[2][1]) + (pa[2][2] + pa[2][3]);           \
        float a3 = (pa[3][0] + pa[3][1]) + (pa[3][2] + pa[3][3]);           \
        float si = 1.f / (1.f + __expf(-a0));                               \
        float sf = 1.f / (1.f + __expf(-a1));                               \
        float tg = 1.f - 2.f / (__expf(2.f * a2) + 1.f);                    \
        float so = 1.f / (1.f + __expf(-a3));                               \
        c = sf * c + si * tg;                                               \
        float tc = 1.f - 2.f / (__expf(2.f * c) + 1.f);                     \
        float h = so * tc;                                                  \
        union { _Float16 hf; unsigned short u; } cv_; cv_.hf = (_Float16)h; \
        unsigned hf_ = cv_.u;                                               \
        unsigned nb_ = (unsigned)__builtin_amdgcn_mov_dpp((int)hf_, 0xB1, 0xF, 0xF, true); \
        hpk = even ? (hf_ | (nb_ << 16)) : (nb_ | (hf_ << 16));             \
        *ep = h;                                                            \
        ep += H_;                                                           \
    }

    for (int t = 0; t < T_; t += 2) {
        STEP(gA, t + 2);
        STEP(gB, t + 3);
    }
#undef STEP
#undef DOTQ
}

extern "C" void kernel_launch(void* const* d_in, const int* in_sizes, int n_in,
                              void* d_out, int out_size, void* d_ws, size_t ws_size,
                              hipStream_t stream) {
    if (n_in < 7 || in_sizes[0] != B_ * T_ * N_) return;

    const float* x    = (const float*)d_in[0];
    const float* aw   = (const float*)d_in[1];
    // d_in[2] (attn_b) provably cancels in the softmax — unused.
    const float* W_ih = (const float*)d_in[3];
    const float* W_hh = (const float*)d_in[4];
    const float* b_ih = (const float*)d_in[5];
    const float* b_hh = (const float*)d_in[6];

    float* iwp = (float*)d_out;                          // (B,T,N) f32
    float* enc = (float*)d_out + (size_t)B_ * T_ * N_;   // (B,T,H) f32

    size_t gx_bytes = (size_t)B_ * T_ * G_ * sizeof(_Float16);   // 33.5 MB
    _Float16* gatesx = (_Float16*)d_ws;
    uint4* wpack = (uint4*)((char*)d_ws + gx_bytes);             // 32 KB
    size_t need = gx_bytes + 2048 * sizeof(uint4);
    if (ws_size < need) return;  // fail loudly rather than corrupt

    hipLaunchKernelGGL(k_wpack, dim3(8), dim3(256), 0, stream, W_hh, wpack);
    hipLaunchKernelGGL(k_awgemm, dim3(B_), dim3(256), 0, stream,
                       x, aw, W_ih, b_ih, b_hh, iwp, gatesx);
    hipLaunchKernelGGL(k_rnn9, dim3(B_), dim3(64), 0, stream, gatesx, wpack, enc);
}

// Round 12
// 184.673 us; speedup vs baseline: 1.6756x; 1.0596x over previous
//
#include <hip/hip_runtime.h>
#include <hip/hip_fp16.h>
#include <cstdint>
#include <cstddef>

#define B_ 512
#define T_ 256
#define N_ 128
#define H_ 64
#define G_ 256  // 4H

typedef __attribute__((ext_vector_type(8))) short short8;
typedef __attribute__((ext_vector_type(4))) float f32x4;
typedef _Float16 half2_t __attribute__((ext_vector_type(2)));

static __device__ __forceinline__ unsigned short f2bf(float f) {
    union { float f; unsigned int i; } v;
    v.f = f;
    unsigned int x = v.i;
    return (unsigned short)((x + 0x7fffu + ((x >> 16) & 1u)) >> 16);  // RNE
}
static __device__ __forceinline__ half2_t u2h2(unsigned int u) {
    union { unsigned int u; half2_t h; } v; v.u = u; return v.h;
}

// ---------------------------------------------------------------------------
// K0: pack W_hh (f32 [4H][H]) -> wpack uint4 [4][8][64]: wpack[g][q][j] =
// half2x4 of W_hh[g*64+j][8q..8q+7].  Exactly the per-lane order k_rnn10 loads.
// ---------------------------------------------------------------------------
__global__ __launch_bounds__(256) void k_wpack(const float* __restrict__ W_hh,
                                               uint4* __restrict__ wpack) {
    int idx = blockIdx.x * 256 + threadIdx.x;   // 2048 entries
    if (idx >= 2048) return;
    int g = idx >> 9, q = (idx >> 6) & 7, j = idx & 63;
    const float* src = W_hh + ((size_t)(g * H_ + j)) * H_ + q * 8;
    float4 a = *(const float4*)(src);
    float4 b = *(const float4*)(src + 4);
    union { uint4 u; half2_t h[4]; } pk;
    pk.h[0] = (half2_t){(_Float16)a.x, (_Float16)a.y};
    pk.h[1] = (half2_t){(_Float16)a.z, (_Float16)a.w};
    pk.h[2] = (half2_t){(_Float16)b.x, (_Float16)b.y};
    pk.h[3] = (half2_t){(_Float16)b.z, (_Float16)b.w};
    wpack[idx] = pk.u;
}

// ---------------------------------------------------------------------------
// K1+K2 fused (unchanged: ~48us, BW floor ~37us — later target).
// ---------------------------------------------------------------------------
__global__ __launch_bounds__(256) void k_awgemm(const float* __restrict__ x,
                                                const float* __restrict__ attn_w,
                                                const float* __restrict__ W_ih,
                                                const float* __restrict__ b_ih,
                                                const float* __restrict__ b_hh,
                                                float* __restrict__ iw,
                                                _Float16* __restrict__ gatesx) {
    __shared__ __align__(16) unsigned short Wl[G_][136];  // bf16 W_ih, padded
    __shared__ __align__(16) unsigned short Al[32][136];  // bf16 wx tile (overlaid: red)
    __shared__ float bias[G_];
    __shared__ float aw_s[T_];
    __shared__ float a_s[N_];
    __shared__ float wred[4];
    const int tid = threadIdx.x;
    const int b = blockIdx.x;

    for (int q = tid; q < G_ * 32; q += 256) {
        int r = q >> 5, c4 = (q & 31) << 2;
        float4 v = *(const float4*)(W_ih + r * N_ + c4);
        Wl[r][c4 + 0] = f2bf(v.x); Wl[r][c4 + 1] = f2bf(v.y);
        Wl[r][c4 + 2] = f2bf(v.z); Wl[r][c4 + 3] = f2bf(v.w);
    }
    bias[tid] = b_ih[tid] + b_hh[tid];
    aw_s[tid] = attn_w[2 * H_ + tid];
    __syncthreads();

    // ---- Phase A: attention softmax (shift-invariance kills h/c/bias) ----
    float (*red)[128] = (float(*)[128])&Al[0][0];
    const int n0 = (tid & 31) << 2;
    const int tg = tid >> 5;
    const float* xb = x + (size_t)b * (T_ * N_);
    {
        float p0 = 0.f, p1 = 0.f, p2 = 0.f, p3 = 0.f;
        for (int t = tg; t < T_; t += 8) {
            float4 v = *(const float4*)(xb + t * N_ + n0);
            float w = aw_s[t];
            p0 += v.x * w; p1 += v.y * w; p2 += v.z * w; p3 += v.w * w;
        }
        red[tg][n0 + 0] = p0; red[tg][n0 + 1] = p1;
        red[tg][n0 + 2] = p2; red[tg][n0 + 3] = p3;
    }
    __syncthreads();
    {
        float s = 0.f;
        if (tid < 128) {
            #pragma unroll
            for (int g = 0; g < 8; ++g) s += red[g][tid];
        }
        float m = (tid < 128) ? s : -1e30f;
        #pragma unroll
        for (int d = 1; d < 64; d <<= 1) m = fmaxf(m, __shfl_xor(m, d));
        if ((tid & 63) == 0) wred[tid >> 6] = m;
        __syncthreads();
        m = fmaxf(wred[0], wred[1]);
        __syncthreads();
        float e = (tid < 128) ? __expf(s - m) : 0.f;
        float z = e;
        #pragma unroll
        for (int d = 1; d < 64; d <<= 1) z += __shfl_xor(z, d);
        if ((tid & 63) == 0) wred[tid >> 6] = z;
        __syncthreads();
        z = wred[0] + wred[1];
        if (tid < 128) a_s[tid] = e / z;
    }
    __syncthreads();

    // ---- Phase B: weighting + MFMA GEMM ----
    const int lane = tid & 63;
    const int lr = lane & 15;
    const int lk = (lane >> 4) << 3;
    const int gc0 = (tid >> 6) << 6;
    const int orow = (lane >> 4) << 2;

    for (int st = 0; st < 8; ++st) {
        const int r0 = b * T_ + st * 32;
        __syncthreads();
        for (int q = tid; q < 32 * 32; q += 256) {
            int r = q >> 5, c4 = (q & 31) << 2;
            size_t off = (size_t)(r0 + r) * N_ + c4;
            float4 v = *(const float4*)(x + off);
            float4 w;
            w.x = a_s[c4 + 0] * v.x; w.y = a_s[c4 + 1] * v.y;
            w.z = a_s[c4 + 2] * v.z; w.w = a_s[c4 + 3] * v.w;
            *(float4*)(iw + off) = w;            // output 0 (f32, exact)
            Al[r][c4 + 0] = f2bf(w.x); Al[r][c4 + 1] = f2bf(w.y);
            Al[r][c4 + 2] = f2bf(w.z); Al[r][c4 + 3] = f2bf(w.w);
        }
        __syncthreads();

        f32x4 acc[2][4];
        #pragma unroll
        for (int mt = 0; mt < 2; ++mt)
            #pragma unroll
            for (int nt = 0; nt < 4; ++nt)
                acc[mt][nt] = (f32x4){0.f, 0.f, 0.f, 0.f};

        #pragma unroll
        for (int kk = 0; kk < N_; kk += 32) {
            short8 af0 = *(const short8*)(&Al[lr][kk + lk]);
            short8 af1 = *(const short8*)(&Al[16 + lr][kk + lk]);
            #pragma unroll
            for (int nt = 0; nt < 4; ++nt) {
                short8 bfv = *(const short8*)(&Wl[gc0 + nt * 16 + lr][kk + lk]);
                acc[0][nt] = __builtin_amdgcn_mfma_f32_16x16x32_bf16(af0, bfv, acc[0][nt], 0, 0, 0);
                acc[1][nt] = __builtin_amdgcn_mfma_f32_16x16x32_bf16(af1, bfv, acc[1][nt], 0, 0, 0);
            }
        }
        // D: col = gc0+nt*16+lr (gate index), row = mt*16+(lane>>4)*4+reg
        #pragma unroll
        for (int mt = 0; mt < 2; ++mt) {
            #pragma unroll
            for (int nt = 0; nt < 4; ++nt) {
                int col = gc0 + nt * 16 + lr;
                float bs = bias[col];
                int cell = col & 63, qg = col >> 6;
                #pragma unroll
                for (int rg = 0; rg < 4; ++rg) {
                    int rr = r0 + mt * 16 + orow + rg;
                    gatesx[((size_t)rr * H_ + cell) * 4 + qg] =
                        (_Float16)(acc[mt][nt][rg] + bs);
                }
            }
        }
    }
}

// ---------------------------------------------------------------------------
// K3: LSTM recurrence, single-wave blocks (64 thr), 512 blocks.
// Round-11 lesson: the ~1250cy/step plateau survived prefetch-depth, dep-chain
// ILP and cross-batch ILP changes -> common factor of all plateaued variants
// is the 32 v_readlane/step (VALU->SGPR->VALU hazard + poor issue rate).
// This round A/Bs that hypothesis directly: identical kernel to k_rnn7 except
// h broadcast is 8x uniform-address ds_read_b128 (same-addr = conflict-free
// broadcast, results in VGPRs, no SGPR hazards); h written back as one
// ds_write_b16. Same-wave DS ops are in-order -> no barriers needed.
// ---------------------------------------------------------------------------
__global__ __attribute__((amdgpu_flat_work_group_size(64, 64)))
__attribute__((amdgpu_waves_per_eu(1, 1)))
void k_rnn10(const _Float16* __restrict__ gatesx,
             const uint4* __restrict__ wpack,
             float* __restrict__ enc) {
    __shared__ __align__(16) _Float16 hs[H_];   // h_t (f16), 128 B
    const int j = threadIdx.x;   // cell index
    const int b = blockIdx.x;

    // 32 x dwordx4 = 128 VGPRs of packed half2 weights (4 gate rows x 8 quads)
    uint4 wv[4][8];
    #pragma unroll
    for (int g = 0; g < 4; ++g) {
        #pragma unroll
        for (int q = 0; q < 8; ++q) {
            unsigned voff = (unsigned)((((g << 3) + q) * 64 + j) << 4);
            asm volatile("global_load_dwordx4 %0, %1, %2"
                         : "=v"(wv[g][q]) : "v"(voff), "s"(wpack) : "memory");
        }
    }
    asm volatile("s_waitcnt vmcnt(0)" ::: "memory");

    hs[j] = (_Float16)0.f;     // h_{-1} = 0 (single wave: DS in-order, no barrier)
    float c = 0.f;

    const _Float16* gx = gatesx + ((size_t)b * T_ * H_ + j) * 4;
    float* ep = enc + (size_t)b * T_ * H_ + j;

    uint2 gA = *(const uint2*)(gx);            // t = 0
    uint2 gB = *(const uint2*)(gx + G_);       // t = 1

#define STEP(GREG, TNEXT)                                                   \
    {                                                                       \
        half2_t gif = u2h2(GREG.x), ggo = u2h2(GREG.y);                     \
        float a0 = (float)gif.x, a1 = (float)gif.y;                         \
        float a2 = (float)ggo.x, a3 = (float)ggo.y;                         \
        int tn_ = (TNEXT) < T_ ? (TNEXT) : (T_ - 1);                        \
        GREG = *(const uint2*)(gx + (size_t)tn_ * G_);                      \
        const uint4* hv4 = (const uint4*)hs;                                \
        _Pragma("unroll")                                                   \
        for (int q = 0; q < 8; ++q) {                                       \
            uint4 ch = hv4[q];        /* uniform addr -> broadcast */       \
            a0 = __builtin_amdgcn_fdot2(u2h2(wv[0][q].x), u2h2(ch.x), a0, false); \
            a1 = __builtin_amdgcn_fdot2(u2h2(wv[1][q].x), u2h2(ch.x), a1, false); \
            a2 = __builtin_amdgcn_fdot2(u2h2(wv[2][q].x), u2h2(ch.x), a2, false); \
            a3 = __builtin_amdgcn_fdot2(u2h2(wv[3][q].x), u2h2(ch.x), a3, false); \
            a0 = __builtin_amdgcn_fdot2(u2h2(wv[0][q].y), u2h2(ch.y), a0, false); \
            a1 = __builtin_amdgcn_fdot2(u2h2(wv[1][q].y), u2h2(ch.y), a1, false); \
            a2 = __builtin_amdgcn_fdot2(u2h2(wv[2][q].y), u2h2(ch.y), a2, false); \
            a3 = __builtin_amdgcn_fdot2(u2h2(wv[3][q].y), u2h2(ch.y), a3, false); \
            a0 = __builtin_amdgcn_fdot2(u2h2(wv[0][q].z), u2h2(ch.z), a0, false); \
            a1 = __builtin_amdgcn_fdot2(u2h2(wv[1][q].z), u2h2(ch.z), a1, false); \
            a2 = __builtin_amdgcn_fdot2(u2h2(wv[2][q].z), u2h2(ch.z), a2, false); \
            a3 = __builtin_amdgcn_fdot2(u2h2(wv[3][q].z), u2h2(ch.z), a3, false); \
            a0 = __builtin_amdgcn_fdot2(u2h2(wv[0][q].w), u2h2(ch.w), a0, false); \
            a1 = __builtin_amdgcn_fdot2(u2h2(wv[1][q].w), u2h2(ch.w), a1, false); \
            a2 = __builtin_amdgcn_fdot2(u2h2(wv[2][q].w), u2h2(ch.w), a2, false); \
            a3 = __builtin_amdgcn_fdot2(u2h2(wv[3][q].w), u2h2(ch.w), a3, false); \
        }                                                                   \
        float si = 1.f / (1.f + __expf(-a0));                               \
        float sf = 1.f / (1.f + __expf(-a1));                               \
        float tg = 1.f - 2.f / (__expf(2.f * a2) + 1.f);                    \
        float so = 1.f / (1.f + __expf(-a3));                               \
        c = sf * c + si * tg;                                               \
        float tc = 1.f - 2.f / (__expf(2.f * c) + 1.f);                     \
        float h = so * tc;                                                  \
        hs[j] = (_Float16)h;      /* in-order DS: visible to next step */   \
        *ep = h;                                                            \
        ep += H_;                                                           \
    }

    for (int t = 0; t < T_; t += 2) {
        STEP(gA, t + 2);
        STEP(gB, t + 3);
    }
#undef STEP
}

extern "C" void kernel_launch(void* const* d_in, const int* in_sizes, int n_in,
                              void* d_out, int out_size, void* d_ws, size_t ws_size,
                              hipStream_t stream) {
    if (n_in < 7 || in_sizes[0] != B_ * T_ * N_) return;

    const float* x    = (const float*)d_in[0];
    const float* aw   = (const float*)d_in[1];
    // d_in[2] (attn_b) provably cancels in the softmax — unused.
    const float* W_ih = (const float*)d_in[3];
    const float* W_hh = (const float*)d_in[4];
    const float* b_ih = (const float*)d_in[5];
    const float* b_hh = (const float*)d_in[6];

    float* iwp = (float*)d_out;                          // (B,T,N) f32
    float* enc = (float*)d_out + (size_t)B_ * T_ * N_;   // (B,T,H) f32

    size_t gx_bytes = (size_t)B_ * T_ * G_ * sizeof(_Float16);   // 33.5 MB
    _Float16* gatesx = (_Float16*)d_ws;
    uint4* wpack = (uint4*)((char*)d_ws + gx_bytes);             // 32 KB
    size_t need = gx_bytes + 2048 * sizeof(uint4);
    if (ws_size < need) return;  // fail loudly rather than corrupt

    hipLaunchKernelGGL(k_wpack, dim3(8), dim3(256), 0, stream, W_hh, wpack);
    hipLaunchKernelGGL(k_awgemm, dim3(B_), dim3(256), 0, stream,
                       x, aw, W_ih, b_ih, b_hh, iwp, gatesx);
    hipLaunchKernelGGL(k_rnn10, dim3(B_), dim3(64), 0, stream, gatesx, wpack, enc);
}